// Round 1
// baseline (48997.263 us; speedup 1.0000x reference)
//
#include <hip/hip_runtime.h>
#include <hip/hip_bf16.h>
#include <math.h>

#define NTOK 197
#define DIMF 768

// ---------------------------------------------------------------------------
// Patch extraction + LayerNorm (one block per patch row, 256 threads, 3 elems each)
// out[b*196+p][768], d = (h1*16+w1)*3 + c
// ---------------------------------------------------------------------------
__global__ __launch_bounds__(256) void patch_ln_k(const float* __restrict__ x,
                                                  float* __restrict__ out,
                                                  const float* __restrict__ g,
                                                  const float* __restrict__ bt) {
    const int r = blockIdx.x;          // 0..12543
    const int t = threadIdx.x;
    const int b = r / 196, p = r % 196;
    const int ph = p / 14, pw = p % 14;

    float v[3];
    #pragma unroll
    for (int i = 0; i < 3; ++i) {
        int d = t + i * 256;
        int c = d % 3;
        int rem = d / 3;
        int w1 = rem % 16;
        int h1 = rem / 16;
        size_t idx = (((size_t)b * 3 + c) * 224 + (ph * 16 + h1)) * 224 + (pw * 16 + w1);
        v[i] = x[idx];
    }
    float s = v[0] + v[1] + v[2];
    float sq = v[0]*v[0] + v[1]*v[1] + v[2]*v[2];
    #pragma unroll
    for (int off = 32; off; off >>= 1) { s += __shfl_xor(s, off); sq += __shfl_xor(sq, off); }
    __shared__ float ss[4], s2[4];
    const int w = t >> 6;
    if ((t & 63) == 0) { ss[w] = s; s2[w] = sq; }
    __syncthreads();
    s  = ss[0] + ss[1] + ss[2] + ss[3];
    sq = s2[0] + s2[1] + s2[2] + s2[3];
    const float inv = 1.0f / 768.0f;
    float mu = s * inv;
    float var = sq * inv - mu * mu;
    float rstd = rsqrtf(var + 1e-5f);
    float* o = out + (size_t)r * 768;
    #pragma unroll
    for (int i = 0; i < 3; ++i) {
        int d = t + i * 256;
        o[d] = (v[i] - mu) * rstd * g[d] + bt[d];
    }
}

// ---------------------------------------------------------------------------
// Row LayerNorm over 768 (one block per row)
// ---------------------------------------------------------------------------
__global__ __launch_bounds__(256) void ln_k(const float* __restrict__ in,
                                            float* __restrict__ out,
                                            const float* __restrict__ g,
                                            const float* __restrict__ bt) {
    const int r = blockIdx.x;
    const int t = threadIdx.x;
    const float* xr = in + (size_t)r * 768;
    float v0 = xr[t], v1 = xr[t + 256], v2 = xr[t + 512];
    float s = v0 + v1 + v2;
    float sq = v0*v0 + v1*v1 + v2*v2;
    #pragma unroll
    for (int off = 32; off; off >>= 1) { s += __shfl_xor(s, off); sq += __shfl_xor(sq, off); }
    __shared__ float ss[4], s2[4];
    const int w = t >> 6;
    if ((t & 63) == 0) { ss[w] = s; s2[w] = sq; }
    __syncthreads();
    s  = ss[0] + ss[1] + ss[2] + ss[3];
    sq = s2[0] + s2[1] + s2[2] + s2[3];
    const float inv = 1.0f / 768.0f;
    float mu = s * inv;
    float var = sq * inv - mu * mu;
    float rstd = rsqrtf(var + 1e-5f);
    float* o = out + (size_t)r * 768;
    o[t]       = (v0 - mu) * rstd * g[t]       + bt[t];
    o[t + 256] = (v1 - mu) * rstd * g[t + 256] + bt[t + 256];
    o[t + 512] = (v2 - mu) * rstd * g[t + 512] + bt[t + 512];
}

// ---------------------------------------------------------------------------
// z = concat(cls, p_ln) + pos  -> [64,197,768]
// ---------------------------------------------------------------------------
__global__ __launch_bounds__(256) void build_z_k(const float* __restrict__ pln,
                                                 const float* __restrict__ cls,
                                                 const float* __restrict__ pos,
                                                 float* __restrict__ z) {
    size_t idx = (size_t)blockIdx.x * 256 + threadIdx.x;   // grid sized exactly
    int d  = idx % 768;
    size_t tkb = idx / 768;
    int tk = tkb % 197;
    int b  = tkb / 197;
    float v = (tk == 0) ? cls[d] : pln[((size_t)b * 196 + (tk - 1)) * 768 + d];
    z[idx] = v + pos[(size_t)tk * 768 + d];
}

// ---------------------------------------------------------------------------
// fp32 tiled GEMM: C = A[M,K] @ W[K,N] (+bias)(+gelu)(+residual)
// BM=BN=128, BK=8, 256 threads, 8x8 per thread.
// EPI: 0 none, 1 +bias, 2 +bias+gelu, 3 +bias+residual
// Requirements: N % 128 == 0, K % 8 == 0. M guarded.
// ---------------------------------------------------------------------------
__device__ __forceinline__ float gelu_f(float x) {
    return 0.5f * x * (1.0f + erff(x * 0.70710678118654752f));
}

template <int EPI>
__global__ __launch_bounds__(256) void gemm_k(const float* __restrict__ A,
                                              const float* __restrict__ W,
                                              const float* __restrict__ bias,
                                              const float* __restrict__ resid,
                                              float* __restrict__ Cout,
                                              int M, int N, int K) {
    __shared__ float As[8][132];
    __shared__ float Bs[8][132];
    const int t  = threadIdx.x;
    const int bm = blockIdx.y * 128;
    const int bn = blockIdx.x * 128;

    const int arow = t >> 1;
    const int ak   = (t & 1) << 2;
    const int bk   = t >> 5;
    const int bcol = (t & 31) << 2;
    const int tm   = t & 15;
    const int tn   = t >> 4;

    float acc[8][8] = {};

    const int  garow = bm + arow;
    const bool aval  = garow < M;
    const float* Aptr = A + (size_t)(aval ? garow : 0) * K + ak;
    const float* Wptr = W + (size_t)bk * N + bn + bcol;

    for (int k0 = 0; k0 < K; k0 += 8) {
        float4 av = aval ? *(const float4*)(Aptr + k0) : make_float4(0.f, 0.f, 0.f, 0.f);
        float4 bv = *(const float4*)(Wptr + (size_t)k0 * N);
        As[ak + 0][arow] = av.x;
        As[ak + 1][arow] = av.y;
        As[ak + 2][arow] = av.z;
        As[ak + 3][arow] = av.w;
        *(float4*)&Bs[bk][bcol] = bv;
        __syncthreads();
        #pragma unroll
        for (int kk = 0; kk < 8; ++kk) {
            float4 a0 = *(const float4*)&As[kk][tm << 2];
            float4 a1 = *(const float4*)&As[kk][64 + (tm << 2)];
            float4 b0 = *(const float4*)&Bs[kk][tn << 2];
            float4 b1 = *(const float4*)&Bs[kk][64 + (tn << 2)];
            float a[8] = {a0.x, a0.y, a0.z, a0.w, a1.x, a1.y, a1.z, a1.w};
            float bb[8] = {b0.x, b0.y, b0.z, b0.w, b1.x, b1.y, b1.z, b1.w};
            #pragma unroll
            for (int i = 0; i < 8; ++i)
                #pragma unroll
                for (int j = 0; j < 8; ++j)
                    acc[i][j] += a[i] * bb[j];
        }
        __syncthreads();
    }

    #pragma unroll
    for (int j4 = 0; j4 < 2; ++j4) {
        const int c0 = bn + j4 * 64 + (tn << 2);
        float4 bias4 = make_float4(0.f, 0.f, 0.f, 0.f);
        if (EPI >= 1) bias4 = *(const float4*)&bias[c0];
        #pragma unroll
        for (int i = 0; i < 8; ++i) {
            const int row = bm + ((i >> 2) << 6) + (tm << 2) + (i & 3);
            if (row < M) {
                float4 v;
                v.x = acc[i][j4 * 4 + 0] + bias4.x;
                v.y = acc[i][j4 * 4 + 1] + bias4.y;
                v.z = acc[i][j4 * 4 + 2] + bias4.z;
                v.w = acc[i][j4 * 4 + 3] + bias4.w;
                if (EPI == 2) {
                    v.x = gelu_f(v.x); v.y = gelu_f(v.y);
                    v.z = gelu_f(v.z); v.w = gelu_f(v.w);
                }
                if (EPI == 3) {
                    float4 rr = *(const float4*)&resid[(size_t)row * N + c0];
                    v.x += rr.x; v.y += rr.y; v.z += rr.z; v.w += rr.w;
                }
                *(float4*)&Cout[(size_t)row * N + c0] = v;
            }
        }
    }
}

// ---------------------------------------------------------------------------
// Fused attention for one (b,h): softmax(Q K^T * 0.125) @ V
// Q,K,V,O layout [B,197,768], head slice = cols h*64..h*64+63.
// 256 threads = 4 waves; K staged in LDS (stride 65); each wave owns rows
// trow = w, w+4, ... Per row: 4 score accumulators per lane (j = lane+64r),
// wave-shuffle softmax, PV with coalesced global V reads.
// ---------------------------------------------------------------------------
__global__ __launch_bounds__(256) void attn_k(const float* __restrict__ Q,
                                              const float* __restrict__ K,
                                              const float* __restrict__ V,
                                              float* __restrict__ O) {
    const int h = blockIdx.x;   // 0..11
    const int b = blockIdx.y;   // 0..63
    __shared__ float Ks[NTOK][65];
    __shared__ float qs[4][64];
    __shared__ float ps[4][200];

    const int t = threadIdx.x;
    const int lane = t & 63;
    const int w = t >> 6;
    const size_t base = ((size_t)b * NTOK) * 768 + h * 64;

    for (int idx = t; idx < NTOK * 64; idx += 256) {
        int j = idx >> 6, d = idx & 63;
        Ks[j][d] = K[base + (size_t)j * 768 + d];
    }
    __syncthreads();

    const int j0 = lane, j1 = lane + 64, j2 = lane + 128, j3 = lane + 192;
    const bool v3 = (j3 < NTOK);
    const int j3c = v3 ? j3 : 0;

    for (int trow = w; trow < NTOK; trow += 4) {
        qs[w][lane] = Q[base + (size_t)trow * 768 + lane];
        float s0 = 0.f, s1 = 0.f, s2 = 0.f, s3 = 0.f;
        #pragma unroll 8
        for (int d = 0; d < 64; ++d) {
            float qd = qs[w][d];
            s0 += qd * Ks[j0][d];
            s1 += qd * Ks[j1][d];
            s2 += qd * Ks[j2][d];
            s3 += qd * Ks[j3c][d];
        }
        const float SC = 0.125f;
        s0 *= SC; s1 *= SC; s2 *= SC;
        s3 = v3 ? s3 * SC : -1e30f;
        float m = fmaxf(fmaxf(s0, s1), fmaxf(s2, s3));
        #pragma unroll
        for (int off = 32; off; off >>= 1) m = fmaxf(m, __shfl_xor(m, off));
        float e0 = __expf(s0 - m), e1 = __expf(s1 - m), e2 = __expf(s2 - m);
        float e3 = v3 ? __expf(s3 - m) : 0.f;
        float sum = e0 + e1 + e2 + e3;
        #pragma unroll
        for (int off = 32; off; off >>= 1) sum += __shfl_xor(sum, off);
        float invs = 1.0f / sum;
        ps[w][j0] = e0 * invs;
        ps[w][j1] = e1 * invs;
        ps[w][j2] = e2 * invs;
        if (v3) ps[w][j3] = e3 * invs;

        float acc = 0.f;
        const float* Vp = V + base + lane;
        #pragma unroll 4
        for (int j = 0; j < NTOK; ++j) acc += ps[w][j] * Vp[(size_t)j * 768];
        O[base + (size_t)trow * 768 + lane] = acc;
    }
}

// ---------------------------------------------------------------------------
// Head: logits = z_ln[b,0,:] @ W_head + b_head ; softmax -> out[b,1000]
// One block per batch element.
// ---------------------------------------------------------------------------
__global__ __launch_bounds__(256) void head_k(const float* __restrict__ xa,
                                              const float* __restrict__ Wh,
                                              const float* __restrict__ bh,
                                              float* __restrict__ out) {
    const int b = blockIdx.x;
    const int t = threadIdx.x;
    __shared__ float zr[768];
    __shared__ float lg[1000];
    __shared__ float red[4];

    for (int d = t; d < 768; d += 256) zr[d] = xa[((size_t)b * 197) * 768 + d];
    __syncthreads();

    for (int c = t; c < 1000; c += 256) {
        float acc = bh[c];
        #pragma unroll 8
        for (int k = 0; k < 768; ++k) acc += zr[k] * Wh[(size_t)k * 1000 + c];
        lg[c] = acc;
    }
    __syncthreads();

    float m = -1e30f;
    for (int c = t; c < 1000; c += 256) m = fmaxf(m, lg[c]);
    #pragma unroll
    for (int off = 32; off; off >>= 1) m = fmaxf(m, __shfl_xor(m, off));
    if ((t & 63) == 0) red[t >> 6] = m;
    __syncthreads();
    m = fmaxf(fmaxf(red[0], red[1]), fmaxf(red[2], red[3]));
    __syncthreads();

    float sum = 0.f;
    for (int c = t; c < 1000; c += 256) sum += __expf(lg[c] - m);
    #pragma unroll
    for (int off = 32; off; off >>= 1) sum += __shfl_xor(sum, off);
    if ((t & 63) == 0) red[t >> 6] = sum;
    __syncthreads();
    sum = red[0] + red[1] + red[2] + red[3];
    const float invs = 1.0f / sum;
    for (int c = t; c < 1000; c += 256) out[(size_t)b * 1000 + c] = __expf(lg[c] - m) * invs;
}

// ---------------------------------------------------------------------------
// Driver
// ---------------------------------------------------------------------------
extern "C" void kernel_launch(void* const* d_in, const int* in_sizes, int n_in,
                              void* d_out, int out_size, void* d_ws, size_t ws_size,
                              hipStream_t stream) {
    const float* x        = (const float*)d_in[0];
    const float* ln_p_g   = (const float*)d_in[1];
    const float* ln_p_b   = (const float*)d_in[2];
    const float* W_patch  = (const float*)d_in[3];
    const float* b_patch  = (const float*)d_in[4];
    const float* ln_e_g   = (const float*)d_in[5];
    const float* ln_e_b   = (const float*)d_in[6];
    const float* pos_emb  = (const float*)d_in[7];
    const float* cls_tok  = (const float*)d_in[8];
    const float* ln_a_g   = (const float*)d_in[9];
    const float* ln_a_b   = (const float*)d_in[10];
    const float* Wq       = (const float*)d_in[11];
    const float* Wk       = (const float*)d_in[12];
    const float* Wv       = (const float*)d_in[13];
    const float* Wo       = (const float*)d_in[14];
    const float* bo       = (const float*)d_in[15];
    const float* ln_f_g   = (const float*)d_in[16];
    const float* ln_f_b   = (const float*)d_in[17];
    const float* W1       = (const float*)d_in[18];
    const float* b1       = (const float*)d_in[19];
    const float* W2       = (const float*)d_in[20];
    const float* b2       = (const float*)d_in[21];
    const float* ln_out_g = (const float*)d_in[22];
    const float* ln_out_b = (const float*)d_in[23];
    const float* W_head   = (const float*)d_in[24];
    const float* b_head   = (const float*)d_in[25];

    float* ws = (float*)d_ws;
    const size_t SZ = (size_t)12608 * 768;      // 9,682,944 floats
    float* Z   = ws;
    float* XA  = ws + SZ;
    float* QB  = ws + 2 * SZ;
    float* KB  = ws + 3 * SZ;
    float* VB  = ws + 4 * SZ;
    float* OB  = ws + 5 * SZ;
    float* FFH = ws + 6 * SZ;                   // 12608*3072 floats

    // patch embed
    patch_ln_k<<<12544, 256, 0, stream>>>(x, XA, ln_p_g, ln_p_b);
    gemm_k<1><<<dim3(6, 98), 256, 0, stream>>>(XA, W_patch, b_patch, nullptr, QB, 12544, 768, 768);
    ln_k<<<12544, 256, 0, stream>>>(QB, KB, ln_e_g, ln_e_b);
    build_z_k<<<37824, 256, 0, stream>>>(KB, cls_tok, pos_emb, Z);

    for (int i = 0; i < 12; ++i) {
        const float* Wq_i = Wq + (size_t)i * 768 * 768;
        const float* Wk_i = Wk + (size_t)i * 768 * 768;
        const float* Wv_i = Wv + (size_t)i * 768 * 768;
        const float* Wo_i = Wo + (size_t)i * 768 * 768;
        const float* bo_i = bo + (size_t)i * 768;
        const float* W1_i = W1 + (size_t)i * 768 * 3072;
        const float* b1_i = b1 + (size_t)i * 3072;
        const float* W2_i = W2 + (size_t)i * 3072 * 768;
        const float* b2_i = b2 + (size_t)i * 768;

        ln_k<<<12608, 256, 0, stream>>>(Z, XA, ln_a_g + (size_t)i * 768, ln_a_b + (size_t)i * 768);
        gemm_k<0><<<dim3(6, 99), 256, 0, stream>>>(XA, Wq_i, nullptr, nullptr, QB, 12608, 768, 768);
        gemm_k<0><<<dim3(6, 99), 256, 0, stream>>>(XA, Wk_i, nullptr, nullptr, KB, 12608, 768, 768);
        gemm_k<0><<<dim3(6, 99), 256, 0, stream>>>(XA, Wv_i, nullptr, nullptr, VB, 12608, 768, 768);
        attn_k<<<dim3(12, 64), 256, 0, stream>>>(QB, KB, VB, OB);
        gemm_k<3><<<dim3(6, 99), 256, 0, stream>>>(OB, Wo_i, bo_i, Z, Z, 12608, 768, 768);
        ln_k<<<12608, 256, 0, stream>>>(Z, XA, ln_f_g + (size_t)i * 768, ln_f_b + (size_t)i * 768);
        gemm_k<2><<<dim3(24, 99), 256, 0, stream>>>(XA, W1_i, b1_i, nullptr, FFH, 12608, 3072, 768);
        gemm_k<3><<<dim3(6, 99), 256, 0, stream>>>(FFH, W2_i, b2_i, Z, Z, 12608, 768, 3072);
    }

    ln_k<<<12608, 256, 0, stream>>>(Z, XA, ln_out_g, ln_out_b);
    head_k<<<64, 256, 0, stream>>>(XA, W_head, b_head, (float*)d_out);
}

// Round 2
// 19628.874 us; speedup vs baseline: 2.4962x; 2.4962x over previous
//
#include <hip/hip_runtime.h>
#include <hip/hip_bf16.h>
#include <math.h>

#define NTOK 197

typedef __attribute__((ext_vector_type(8))) short bfx8;
typedef __attribute__((ext_vector_type(4))) float fx4;

#define GLOAD16(gsrc, ldst) __builtin_amdgcn_global_load_lds( \
    (const __attribute__((address_space(1))) void*)(gsrc),    \
    (__attribute__((address_space(3))) void*)(ldst), 16, 0, 0)

__device__ __forceinline__ float bf2f(unsigned short x) {
    return __uint_as_float(((unsigned)x) << 16);
}
__device__ __forceinline__ float gelu_f(float x) {
    return 0.5f * x * (1.0f + erff(x * 0.70710678118654752f));
}

// ---------------------------------------------------------------------------
// Patch extraction + LayerNorm -> bf16 (one block per patch row)
// ---------------------------------------------------------------------------
__global__ __launch_bounds__(256) void patch_ln_k(const float* __restrict__ x,
                                                  __hip_bfloat16* __restrict__ out,
                                                  const float* __restrict__ g,
                                                  const float* __restrict__ bt) {
    const int r = blockIdx.x;          // 0..12543
    const int t = threadIdx.x;
    const int b = r / 196, p = r % 196;
    const int ph = p / 14, pw = p % 14;

    float v[3];
    #pragma unroll
    for (int i = 0; i < 3; ++i) {
        int d = t + i * 256;
        int c = d % 3;
        int rem = d / 3;
        int w1 = rem % 16;
        int h1 = rem / 16;
        size_t idx = (((size_t)b * 3 + c) * 224 + (ph * 16 + h1)) * 224 + (pw * 16 + w1);
        v[i] = x[idx];
    }
    float s = v[0] + v[1] + v[2];
    float sq = v[0]*v[0] + v[1]*v[1] + v[2]*v[2];
    #pragma unroll
    for (int off = 32; off; off >>= 1) { s += __shfl_xor(s, off); sq += __shfl_xor(sq, off); }
    __shared__ float ss[4], s2[4];
    const int w = t >> 6;
    if ((t & 63) == 0) { ss[w] = s; s2[w] = sq; }
    __syncthreads();
    s  = ss[0] + ss[1] + ss[2] + ss[3];
    sq = s2[0] + s2[1] + s2[2] + s2[3];
    const float inv = 1.0f / 768.0f;
    float mu = s * inv;
    float var = sq * inv - mu * mu;
    float rstd = rsqrtf(var + 1e-5f);
    __hip_bfloat16* o = out + (size_t)r * 768;
    #pragma unroll
    for (int i = 0; i < 3; ++i) {
        int d = t + i * 256;
        o[d] = (__hip_bfloat16)((v[i] - mu) * rstd * g[d] + bt[d]);
    }
}

// ---------------------------------------------------------------------------
// Row LayerNorm over 768 fp32 -> OT
// ---------------------------------------------------------------------------
template <typename OT>
__global__ __launch_bounds__(256) void ln_k(const float* __restrict__ in,
                                            OT* __restrict__ out,
                                            const float* __restrict__ g,
                                            const float* __restrict__ bt) {
    const int r = blockIdx.x;
    const int t = threadIdx.x;
    const float* xr = in + (size_t)r * 768;
    float v0 = xr[t], v1 = xr[t + 256], v2 = xr[t + 512];
    float s = v0 + v1 + v2;
    float sq = v0*v0 + v1*v1 + v2*v2;
    #pragma unroll
    for (int off = 32; off; off >>= 1) { s += __shfl_xor(s, off); sq += __shfl_xor(sq, off); }
    __shared__ float ss[4], s2[4];
    const int w = t >> 6;
    if ((t & 63) == 0) { ss[w] = s; s2[w] = sq; }
    __syncthreads();
    s  = ss[0] + ss[1] + ss[2] + ss[3];
    sq = s2[0] + s2[1] + s2[2] + s2[3];
    const float inv = 1.0f / 768.0f;
    float mu = s * inv;
    float var = sq * inv - mu * mu;
    float rstd = rsqrtf(var + 1e-5f);
    OT* o = out + (size_t)r * 768;
    o[t]       = (OT)((v0 - mu) * rstd * g[t]       + bt[t]);
    o[t + 256] = (OT)((v1 - mu) * rstd * g[t + 256] + bt[t + 256]);
    o[t + 512] = (OT)((v2 - mu) * rstd * g[t + 512] + bt[t + 512]);
}

// ---------------------------------------------------------------------------
// z = concat(cls, p_ln) + pos  -> [64,197,768] fp32
// ---------------------------------------------------------------------------
__global__ __launch_bounds__(256) void build_z_k(const float* __restrict__ pln,
                                                 const float* __restrict__ cls,
                                                 const float* __restrict__ pos,
                                                 float* __restrict__ z) {
    size_t idx = (size_t)blockIdx.x * 256 + threadIdx.x;
    int d  = idx % 768;
    size_t tkb = idx / 768;
    int tk = tkb % 197;
    int b  = tkb / 197;
    float v = (tk == 0) ? cls[d] : pln[((size_t)b * 196 + (tk - 1)) * 768 + d];
    z[idx] = v + pos[(size_t)tk * 768 + d];
}

// ---------------------------------------------------------------------------
// Weight convert + transpose: fp32 [K,N] -> bf16 [N,K], one matrix per z
// ---------------------------------------------------------------------------
__global__ __launch_bounds__(256) void wconv_k(const float* __restrict__ W,
                                               __hip_bfloat16* __restrict__ Wt,
                                               int K, int N) {
    __shared__ float tl[64][65];
    const int t = threadIdx.x;
    const int n0 = blockIdx.x * 64, k0 = blockIdx.y * 64;
    const size_t ibase = (size_t)blockIdx.z * K * N;
    const size_t obase = (size_t)blockIdx.z * K * N;
    #pragma unroll
    for (int i = 0; i < 16; ++i) {
        int idx = i * 256 + t;
        int kl = idx >> 6, nl = idx & 63;
        tl[kl][nl] = W[ibase + (size_t)(k0 + kl) * N + n0 + nl];
    }
    __syncthreads();
    #pragma unroll
    for (int i = 0; i < 16; ++i) {
        int idx = i * 256 + t;
        int nl = idx >> 6, kl = idx & 63;
        Wt[obase + (size_t)(n0 + nl) * K + k0 + kl] = (__hip_bfloat16)tl[kl][nl];
    }
}

// ---------------------------------------------------------------------------
// bf16 MFMA GEMM: C = A[M,K](bf16) @ Wt[N,K]^T (+bias)(+gelu)(+residual)
// BM=BN=128, BK=32, 256 threads (4 waves, 2x2), 16x16x32 MFMA, 4x4 frags/wave.
// LDS tiles staged via global_load_lds w/ XOR-chunk swizzle on global source.
// EPI: 0 none, 1 +bias, 2 +bias+gelu, 3 +bias+residual. Stores guarded row<M.
// A must be readable for all tile rows (pad M to grid*128 rows).
// ---------------------------------------------------------------------------
template <int EPI, typename OT>
__global__ __launch_bounds__(256) void mgemm_k(const __hip_bfloat16* __restrict__ A,
                                               const __hip_bfloat16* __restrict__ Wt,
                                               const float* __restrict__ bias,
                                               const float* __restrict__ resid,
                                               OT* __restrict__ C,
                                               int M, int N, int K) {
    __shared__ __align__(16) char sA[8192];
    __shared__ __align__(16) char sB[8192];
    const int t = threadIdx.x;
    const int lane = t & 63, w = t >> 6;
    const int wr = w >> 1, wc = w & 1;
    const int lrow = lane & 15, lgr = lane >> 4;
    const int bm = blockIdx.y * 128, bn = blockIdx.x * 128;

    // staging: 512 chunks of 16B per tile; thread handles chunk t and t+256
    const int q0 = t, q1 = t + 256;
    const int r0 = q0 >> 2, r1 = q1 >> 2;
    const int g0 = (q0 & 3) ^ ((r0 >> 1) & 3);
    const int g1 = (q1 & 3) ^ ((r1 >> 1) & 3);
    const __hip_bfloat16* a0 = A + (size_t)(bm + r0) * K + g0 * 8;
    const __hip_bfloat16* a1 = A + (size_t)(bm + r1) * K + g1 * 8;
    const __hip_bfloat16* b0 = Wt + (size_t)(bn + r0) * K + g0 * 8;
    const __hip_bfloat16* b1 = Wt + (size_t)(bn + r1) * K + g1 * 8;
    char* da0 = sA + q0 * 16; char* da1 = sA + q1 * 16;
    char* db0 = sB + q0 * 16; char* db1 = sB + q1 * 16;

    int aoff[4], boff[4];
    #pragma unroll
    for (int m = 0; m < 4; ++m) {
        int ra = wr * 64 + m * 16 + lrow;
        aoff[m] = ra * 64 + ((lgr ^ ((ra >> 1) & 3)) << 4);
        int rb = wc * 64 + m * 16 + lrow;
        boff[m] = rb * 64 + ((lgr ^ ((rb >> 1) & 3)) << 4);
    }

    fx4 acc[4][4];
    #pragma unroll
    for (int m = 0; m < 4; ++m)
        #pragma unroll
        for (int n = 0; n < 4; ++n)
            #pragma unroll
            for (int e = 0; e < 4; ++e) acc[m][n][e] = 0.f;

    for (int k0 = 0; k0 < K; k0 += 32) {
        GLOAD16(a0 + k0, da0);
        GLOAD16(a1 + k0, da1);
        GLOAD16(b0 + k0, db0);
        GLOAD16(b1 + k0, db1);
        __syncthreads();
        bfx8 av[4], bv[4];
        #pragma unroll
        for (int m = 0; m < 4; ++m) {
            av[m] = *(const bfx8*)(sA + aoff[m]);
            bv[m] = *(const bfx8*)(sB + boff[m]);
        }
        #pragma unroll
        for (int m = 0; m < 4; ++m)
            #pragma unroll
            for (int n = 0; n < 4; ++n)
                acc[m][n] = __builtin_amdgcn_mfma_f32_16x16x32_bf16(av[m], bv[n], acc[m][n], 0, 0, 0);
        __syncthreads();
    }

    #pragma unroll
    for (int m = 0; m < 4; ++m) {
        #pragma unroll
        for (int n = 0; n < 4; ++n) {
            const int col = bn + wc * 64 + n * 16 + lrow;
            float bv2 = (EPI >= 1) ? bias[col] : 0.f;
            #pragma unroll
            for (int e = 0; e < 4; ++e) {
                const int row = bm + wr * 64 + m * 16 + lgr * 4 + e;
                if (row < M) {
                    float v = acc[m][n][e] + bv2;
                    if (EPI == 2) v = gelu_f(v);
                    if (EPI == 3) v += resid[(size_t)row * N + col];
                    C[(size_t)row * N + col] = (OT)v;
                }
            }
        }
    }
}

// ---------------------------------------------------------------------------
// Fused attention, bf16 in/out. One block per (h,b): K,V staged in LDS bf16
// with XOR 16B-chunk swizzle (row = 128B). 4 waves; wave handles rows w,w+4,...
// ---------------------------------------------------------------------------
__global__ __launch_bounds__(256) void attn_k(const __hip_bfloat16* __restrict__ Q,
                                              const __hip_bfloat16* __restrict__ K,
                                              const __hip_bfloat16* __restrict__ V,
                                              __hip_bfloat16* __restrict__ O) {
    __shared__ __align__(16) char Ks[NTOK * 128];
    __shared__ __align__(16) char Vs[NTOK * 128];
    __shared__ float qs[4][64];
    __shared__ float ps[4][200];

    const int h = blockIdx.x;
    const int b = blockIdx.y;
    const int t = threadIdx.x;
    const int lane = t & 63, w = t >> 6;
    const size_t base = ((size_t)b * NTOK) * 768 + h * 64;

    // stage K,V: 1576 16B chunks each, source pre-swizzled so LDS is linear
    for (int q = t; q < NTOK * 8; q += 256) {
        int j = q >> 3, c = q & 7;
        int gc = c ^ (j & 7);
        GLOAD16(K + base + (size_t)j * 768 + gc * 8, Ks + q * 16);
        GLOAD16(V + base + (size_t)j * 768 + gc * 8, Vs + q * 16);
    }
    __syncthreads();

    const int coff = (lane >> 3) << 4;     // V chunk byte for d=lane
    const int dlow = (lane & 7) << 1;

    for (int trow = w; trow < NTOK; trow += 4) {
        qs[w][lane] = bf2f(((const unsigned short*)Q)[base + (size_t)trow * 768 + lane]);
        float s[4];
        #pragma unroll
        for (int g = 0; g < 4; ++g) {
            int j = lane + g * 64;
            bool val = j < NTOK;
            int jj = val ? j : 0;
            const char* kr = Ks + jj * 128;
            const int sw = (jj & 7) << 4;
            float acc = 0.f;
            #pragma unroll
            for (int c = 0; c < 8; ++c) {
                bfx8 kv = *(const bfx8*)(kr + ((c << 4) ^ sw));
                float4 qa = *(const float4*)&qs[w][c * 8];
                float4 qb = *(const float4*)&qs[w][c * 8 + 4];
                acc += qa.x * bf2f((unsigned short)kv[0]) + qa.y * bf2f((unsigned short)kv[1])
                     + qa.z * bf2f((unsigned short)kv[2]) + qa.w * bf2f((unsigned short)kv[3])
                     + qb.x * bf2f((unsigned short)kv[4]) + qb.y * bf2f((unsigned short)kv[5])
                     + qb.z * bf2f((unsigned short)kv[6]) + qb.w * bf2f((unsigned short)kv[7]);
            }
            s[g] = val ? acc * 0.125f : -1e30f;
        }
        float m0 = fmaxf(fmaxf(s[0], s[1]), fmaxf(s[2], s[3]));
        #pragma unroll
        for (int off = 32; off; off >>= 1) m0 = fmaxf(m0, __shfl_xor(m0, off));
        float e0 = __expf(s[0] - m0), e1 = __expf(s[1] - m0);
        float e2 = __expf(s[2] - m0), e3 = (lane < 5) ? __expf(s[3] - m0) : 0.f;
        float sum = e0 + e1 + e2 + e3;
        #pragma unroll
        for (int off = 32; off; off >>= 1) sum += __shfl_xor(sum, off);
        float inv = 1.0f / sum;
        ps[w][lane]       = e0 * inv;
        ps[w][lane + 64]  = e1 * inv;
        ps[w][lane + 128] = e2 * inv;
        if (lane < 5) ps[w][lane + 192] = e3 * inv;

        float oacc = 0.f;
        for (int j4 = 0; j4 < 49; ++j4) {
            float4 pv = *(const float4*)&ps[w][j4 * 4];
            #pragma unroll
            for (int u = 0; u < 4; ++u) {
                int j = j4 * 4 + u;
                unsigned short vv = *(const unsigned short*)(Vs + j * 128 + (coff ^ ((j & 7) << 4)) + dlow);
                float pf = (u == 0) ? pv.x : (u == 1) ? pv.y : (u == 2) ? pv.z : pv.w;
                oacc += pf * bf2f(vv);
            }
        }
        {
            int j = 196;
            unsigned short vv = *(const unsigned short*)(Vs + j * 128 + (coff ^ ((j & 7) << 4)) + dlow);
            oacc += ps[w][j] * bf2f(vv);
        }
        O[base + (size_t)trow * 768 + lane] = (__hip_bfloat16)oacc;
    }
}

// ---------------------------------------------------------------------------
// Head: logits = z_ln[b,0,:] @ W_head + b_head ; softmax -> out[b,1000]
// ---------------------------------------------------------------------------
__global__ __launch_bounds__(256) void head_k(const float* __restrict__ xa,
                                              const float* __restrict__ Wh,
                                              const float* __restrict__ bh,
                                              float* __restrict__ out) {
    const int b = blockIdx.x;
    const int t = threadIdx.x;
    __shared__ float zr[768];
    __shared__ float lg[1000];
    __shared__ float red[4];

    for (int d = t; d < 768; d += 256) zr[d] = xa[((size_t)b * 197) * 768 + d];
    __syncthreads();

    for (int c = t; c < 1000; c += 256) {
        float acc = bh[c];
        #pragma unroll 8
        for (int k = 0; k < 768; ++k) acc += zr[k] * Wh[(size_t)k * 1000 + c];
        lg[c] = acc;
    }
    __syncthreads();

    float m = -1e30f;
    for (int c = t; c < 1000; c += 256) m = fmaxf(m, lg[c]);
    #pragma unroll
    for (int off = 32; off; off >>= 1) m = fmaxf(m, __shfl_xor(m, off));
    if ((t & 63) == 0) red[t >> 6] = m;
    __syncthreads();
    m = fmaxf(fmaxf(red[0], red[1]), fmaxf(red[2], red[3]));
    __syncthreads();

    float sum = 0.f;
    for (int c = t; c < 1000; c += 256) sum += __expf(lg[c] - m);
    #pragma unroll
    for (int off = 32; off; off >>= 1) sum += __shfl_xor(sum, off);
    if ((t & 63) == 0) red[t >> 6] = sum;
    __syncthreads();
    sum = red[0] + red[1] + red[2] + red[3];
    const float invs = 1.0f / sum;
    for (int c = t; c < 1000; c += 256) out[(size_t)b * 1000 + c] = __expf(lg[c] - m) * invs;
}

// ---------------------------------------------------------------------------
// Driver
// ---------------------------------------------------------------------------
extern "C" void kernel_launch(void* const* d_in, const int* in_sizes, int n_in,
                              void* d_out, int out_size, void* d_ws, size_t ws_size,
                              hipStream_t stream) {
    const float* x        = (const float*)d_in[0];
    const float* ln_p_g   = (const float*)d_in[1];
    const float* ln_p_b   = (const float*)d_in[2];
    const float* W_patch  = (const float*)d_in[3];
    const float* b_patch  = (const float*)d_in[4];
    const float* ln_e_g   = (const float*)d_in[5];
    const float* ln_e_b   = (const float*)d_in[6];
    const float* pos_emb  = (const float*)d_in[7];
    const float* cls_tok  = (const float*)d_in[8];
    const float* ln_a_g   = (const float*)d_in[9];
    const float* ln_a_b   = (const float*)d_in[10];
    const float* Wq       = (const float*)d_in[11];
    const float* Wk       = (const float*)d_in[12];
    const float* Wv       = (const float*)d_in[13];
    const float* Wo       = (const float*)d_in[14];
    const float* bo       = (const float*)d_in[15];
    const float* ln_f_g   = (const float*)d_in[16];
    const float* ln_f_b   = (const float*)d_in[17];
    const float* W1       = (const float*)d_in[18];
    const float* b1       = (const float*)d_in[19];
    const float* W2       = (const float*)d_in[20];
    const float* b2       = (const float*)d_in[21];
    const float* ln_out_g = (const float*)d_in[22];
    const float* ln_out_b = (const float*)d_in[23];
    const float* W_head   = (const float*)d_in[24];
    const float* b_head   = (const float*)d_in[25];

    typedef __hip_bfloat16 bf;
    const int M  = 12608;               // 64*197
    const int MP = 12672;               // padded to 99*128
    char* p = (char*)d_ws;

    float* Z   = (float*)p;            p += (size_t)MP * 768 * 4;      // fp32 residual
    bf* XA     = (bf*)p;               p += (size_t)MP * 768 * 2;      // LN out (bf16)
    bf* QB     = (bf*)p;               p += (size_t)MP * 768 * 2;
    bf* KB     = (bf*)p;               p += (size_t)MP * 768 * 2;
    bf* VB     = (bf*)p;               p += (size_t)MP * 768 * 2;
    bf* OB     = (bf*)p;               p += (size_t)MP * 768 * 2;
    char* FFHc = p;                    p += (size_t)MP * 3072 * 2;     // bf16 GELU buf
    bf* FFH    = (bf*)FFHc;
    float* PE  = (float*)FFHc;                                          // alias: patch-embed fp32
    float* E2  = (float*)(FFHc + (size_t)MP * 768 * 4);                 // alias: ln_e out fp32
    float* FLN = (float*)FFHc;                                          // alias: final LN fp32
    bf* WqT    = (bf*)p;               p += (size_t)12 * 768 * 768 * 2;
    bf* WkT    = (bf*)p;               p += (size_t)12 * 768 * 768 * 2;
    bf* WvT    = (bf*)p;               p += (size_t)12 * 768 * 768 * 2;
    bf* WoT    = (bf*)p;               p += (size_t)12 * 768 * 768 * 2;
    bf* W1T    = (bf*)p;               p += (size_t)12 * 3072 * 768 * 2;
    bf* W2T    = (bf*)p;               p += (size_t)12 * 768 * 3072 * 2;
    bf* WpT    = (bf*)p;               p += (size_t)768 * 768 * 2;

    // weight convert + transpose (every launch; ~510 MB traffic)
    wconv_k<<<dim3(12, 12, 12), 256, 0, stream>>>(Wq, WqT, 768, 768);
    wconv_k<<<dim3(12, 12, 12), 256, 0, stream>>>(Wk, WkT, 768, 768);
    wconv_k<<<dim3(12, 12, 12), 256, 0, stream>>>(Wv, WvT, 768, 768);
    wconv_k<<<dim3(12, 12, 12), 256, 0, stream>>>(Wo, WoT, 768, 768);
    wconv_k<<<dim3(48, 12, 12), 256, 0, stream>>>(W1, W1T, 768, 3072);
    wconv_k<<<dim3(12, 48, 12), 256, 0, stream>>>(W2, W2T, 3072, 768);
    wconv_k<<<dim3(12, 12, 1),  256, 0, stream>>>(W_patch, WpT, 768, 768);

    // patch embed pipeline
    patch_ln_k<<<12544, 256, 0, stream>>>(x, XA, ln_p_g, ln_p_b);
    mgemm_k<1, float><<<dim3(6, 98), 256, 0, stream>>>(XA, WpT, b_patch, nullptr, PE, 12544, 768, 768);
    ln_k<float><<<12544, 256, 0, stream>>>(PE, E2, ln_e_g, ln_e_b);
    build_z_k<<<37824, 256, 0, stream>>>(E2, cls_tok, pos_emb, Z);

    for (int i = 0; i < 12; ++i) {
        bf* WqT_i = WqT + (size_t)i * 768 * 768;
        bf* WkT_i = WkT + (size_t)i * 768 * 768;
        bf* WvT_i = WvT + (size_t)i * 768 * 768;
        bf* WoT_i = WoT + (size_t)i * 768 * 768;
        bf* W1T_i = W1T + (size_t)i * 3072 * 768;
        bf* W2T_i = W2T + (size_t)i * 768 * 3072;

        ln_k<bf><<<M, 256, 0, stream>>>(Z, XA, ln_a_g + (size_t)i * 768, ln_a_b + (size_t)i * 768);
        mgemm_k<0, bf><<<dim3(6, 99), 256, 0, stream>>>(XA, WqT_i, nullptr, nullptr, QB, M, 768, 768);
        mgemm_k<0, bf><<<dim3(6, 99), 256, 0, stream>>>(XA, WkT_i, nullptr, nullptr, KB, M, 768, 768);
        mgemm_k<0, bf><<<dim3(6, 99), 256, 0, stream>>>(XA, WvT_i, nullptr, nullptr, VB, M, 768, 768);
        attn_k<<<dim3(12, 64), 256, 0, stream>>>(QB, KB, VB, OB);
        mgemm_k<3, float><<<dim3(6, 99), 256, 0, stream>>>(OB, WoT_i, bo + (size_t)i * 768, Z, Z, M, 768, 768);
        ln_k<bf><<<M, 256, 0, stream>>>(Z, XA, ln_f_g + (size_t)i * 768, ln_f_b + (size_t)i * 768);
        mgemm_k<2, bf><<<dim3(24, 99), 256, 0, stream>>>(XA, W1T_i, b1 + (size_t)i * 3072, nullptr, FFH, M, 3072, 768);
        mgemm_k<3, float><<<dim3(6, 99), 256, 0, stream>>>(FFH, W2T_i, b2 + (size_t)i * 768, Z, Z, M, 768, 3072);
    }

    ln_k<float><<<M, 256, 0, stream>>>(Z, FLN, ln_out_g, ln_out_b);
    head_k<<<64, 256, 0, stream>>>(FLN, W_head, b_head, (float*)d_out);
}

// Round 4
// 6182.117 us; speedup vs baseline: 7.9256x; 3.1751x over previous
//
#include <hip/hip_runtime.h>
#include <hip/hip_bf16.h>
#include <math.h>

#define NTOK 197

typedef __attribute__((ext_vector_type(8))) short bfx8;
typedef __attribute__((ext_vector_type(4))) float fx4;

#define GLOAD16(gsrc, ldst) __builtin_amdgcn_global_load_lds( \
    (const __attribute__((address_space(1))) void*)(gsrc),    \
    (__attribute__((address_space(3))) void*)(ldst), 16, 0, 0)

__device__ __forceinline__ float bf2f(unsigned short x) {
    return __uint_as_float(((unsigned)x) << 16);
}
__device__ __forceinline__ float gelu_f(float x) {
    return 0.5f * x * (1.0f + erff(x * 0.70710678118654752f));
}

// ---------------------------------------------------------------------------
// Patch extraction + LayerNorm -> bf16 (one block per patch row)
// ---------------------------------------------------------------------------
__global__ __launch_bounds__(256) void patch_ln_k(const float* __restrict__ x,
                                                  __hip_bfloat16* __restrict__ out,
                                                  const float* __restrict__ g,
                                                  const float* __restrict__ bt) {
    const int r = blockIdx.x;          // 0..12543
    const int t = threadIdx.x;
    const int b = r / 196, p = r % 196;
    const int ph = p / 14, pw = p % 14;

    float v[3];
    #pragma unroll
    for (int i = 0; i < 3; ++i) {
        int d = t + i * 256;
        int c = d % 3;
        int rem = d / 3;
        int w1 = rem % 16;
        int h1 = rem / 16;
        size_t idx = (((size_t)b * 3 + c) * 224 + (ph * 16 + h1)) * 224 + (pw * 16 + w1);
        v[i] = x[idx];
    }
    float s = v[0] + v[1] + v[2];
    float sq = v[0]*v[0] + v[1]*v[1] + v[2]*v[2];
    #pragma unroll
    for (int off = 32; off; off >>= 1) { s += __shfl_xor(s, off); sq += __shfl_xor(sq, off); }
    __shared__ float ss[4], s2[4];
    const int w = t >> 6;
    if ((t & 63) == 0) { ss[w] = s; s2[w] = sq; }
    __syncthreads();
    s  = ss[0] + ss[1] + ss[2] + ss[3];
    sq = s2[0] + s2[1] + s2[2] + s2[3];
    const float inv = 1.0f / 768.0f;
    float mu = s * inv;
    float var = sq * inv - mu * mu;
    float rstd = rsqrtf(var + 1e-5f);
    __hip_bfloat16* o = out + (size_t)r * 768;
    #pragma unroll
    for (int i = 0; i < 3; ++i) {
        int d = t + i * 256;
        o[d] = (__hip_bfloat16)((v[i] - mu) * rstd * g[d] + bt[d]);
    }
}

// ---------------------------------------------------------------------------
// Row LayerNorm over 768 fp32 -> OT
// ---------------------------------------------------------------------------
template <typename OT>
__global__ __launch_bounds__(256) void ln_k(const float* __restrict__ in,
                                            OT* __restrict__ out,
                                            const float* __restrict__ g,
                                            const float* __restrict__ bt) {
    const int r = blockIdx.x;
    const int t = threadIdx.x;
    const float* xr = in + (size_t)r * 768;
    float v0 = xr[t], v1 = xr[t + 256], v2 = xr[t + 512];
    float s = v0 + v1 + v2;
    float sq = v0*v0 + v1*v1 + v2*v2;
    #pragma unroll
    for (int off = 32; off; off >>= 1) { s += __shfl_xor(s, off); sq += __shfl_xor(sq, off); }
    __shared__ float ss[4], s2[4];
    const int w = t >> 6;
    if ((t & 63) == 0) { ss[w] = s; s2[w] = sq; }
    __syncthreads();
    s  = ss[0] + ss[1] + ss[2] + ss[3];
    sq = s2[0] + s2[1] + s2[2] + s2[3];
    const float inv = 1.0f / 768.0f;
    float mu = s * inv;
    float var = sq * inv - mu * mu;
    float rstd = rsqrtf(var + 1e-5f);
    OT* o = out + (size_t)r * 768;
    o[t]       = (OT)((v0 - mu) * rstd * g[t]       + bt[t]);
    o[t + 256] = (OT)((v1 - mu) * rstd * g[t + 256] + bt[t + 256]);
    o[t + 512] = (OT)((v2 - mu) * rstd * g[t + 512] + bt[t + 512]);
}

// ---------------------------------------------------------------------------
// z = concat(cls, p_ln) + pos  -> [64,197,768] fp32
// ---------------------------------------------------------------------------
__global__ __launch_bounds__(256) void build_z_k(const float* __restrict__ pln,
                                                 const float* __restrict__ cls,
                                                 const float* __restrict__ pos,
                                                 float* __restrict__ z) {
    size_t idx = (size_t)blockIdx.x * 256 + threadIdx.x;
    int d  = idx % 768;
    size_t tkb = idx / 768;
    int tk = tkb % 197;
    int b  = tkb / 197;
    float v = (tk == 0) ? cls[d] : pln[((size_t)b * 196 + (tk - 1)) * 768 + d];
    z[idx] = v + pos[(size_t)tk * 768 + d];
}

// ---------------------------------------------------------------------------
// Weight convert + transpose: fp32 [K,N] -> bf16 [N,K], one matrix per z
// ---------------------------------------------------------------------------
__global__ __launch_bounds__(256) void wconv_k(const float* __restrict__ W,
                                               __hip_bfloat16* __restrict__ Wt,
                                               int K, int N) {
    __shared__ float tl[64][65];
    const int t = threadIdx.x;
    const int n0 = blockIdx.x * 64, k0 = blockIdx.y * 64;
    const size_t ibase = (size_t)blockIdx.z * K * N;
    const size_t obase = (size_t)blockIdx.z * K * N;
    #pragma unroll
    for (int i = 0; i < 16; ++i) {
        int idx = i * 256 + t;
        int kl = idx >> 6, nl = idx & 63;
        tl[kl][nl] = W[ibase + (size_t)(k0 + kl) * N + n0 + nl];
    }
    __syncthreads();
    #pragma unroll
    for (int i = 0; i < 16; ++i) {
        int idx = i * 256 + t;
        int nl = idx >> 6, kl = idx & 63;
        Wt[obase + (size_t)(n0 + nl) * K + k0 + kl] = (__hip_bfloat16)tl[kl][nl];
    }
}

// ---------------------------------------------------------------------------
// bf16 MFMA GEMM (m97 structure): C = A[M,K](bf16) @ Wt[N,K]^T (+epilogue)
// ---------------------------------------------------------------------------
template <int EPI, typename OT>
__global__ __launch_bounds__(256) void mgemm_k(const __hip_bfloat16* __restrict__ A,
                                               const __hip_bfloat16* __restrict__ Wt,
                                               const float* __restrict__ bias,
                                               const float* __restrict__ resid,
                                               OT* __restrict__ C,
                                               int M, int N, int K) {
    __shared__ __align__(16) char sA[8192];
    __shared__ __align__(16) char sB[8192];
    const int t = threadIdx.x;
    const int lane = t & 63, w = t >> 6;
    const int wr = w >> 1, wc = w & 1;
    const int lrow = lane & 15, lgr = lane >> 4;
    const int bm = blockIdx.y * 128, bn = blockIdx.x * 128;

    const int q0 = t, q1 = t + 256;
    const int r0 = q0 >> 2, r1 = q1 >> 2;
    const int g0 = (q0 & 3) ^ ((r0 >> 1) & 3);
    const int g1 = (q1 & 3) ^ ((r1 >> 1) & 3);
    const __hip_bfloat16* a0 = A + (size_t)(bm + r0) * K + g0 * 8;
    const __hip_bfloat16* a1 = A + (size_t)(bm + r1) * K + g1 * 8;
    const __hip_bfloat16* b0 = Wt + (size_t)(bn + r0) * K + g0 * 8;
    const __hip_bfloat16* b1 = Wt + (size_t)(bn + r1) * K + g1 * 8;
    char* da0 = sA + q0 * 16; char* da1 = sA + q1 * 16;
    char* db0 = sB + q0 * 16; char* db1 = sB + q1 * 16;

    int aoff[4], boff[4];
    #pragma unroll
    for (int m = 0; m < 4; ++m) {
        int ra = wr * 64 + m * 16 + lrow;
        aoff[m] = ra * 64 + ((lgr ^ ((ra >> 1) & 3)) << 4);
        int rb = wc * 64 + m * 16 + lrow;
        boff[m] = rb * 64 + ((lgr ^ ((rb >> 1) & 3)) << 4);
    }

    fx4 acc[4][4];
    #pragma unroll
    for (int m = 0; m < 4; ++m)
        #pragma unroll
        for (int n = 0; n < 4; ++n)
            #pragma unroll
            for (int e = 0; e < 4; ++e) acc[m][n][e] = 0.f;

    for (int k0 = 0; k0 < K; k0 += 32) {
        GLOAD16(a0 + k0, da0);
        GLOAD16(a1 + k0, da1);
        GLOAD16(b0 + k0, db0);
        GLOAD16(b1 + k0, db1);
        __syncthreads();
        bfx8 av[4], bv[4];
        #pragma unroll
        for (int m = 0; m < 4; ++m) {
            av[m] = *(const bfx8*)(sA + aoff[m]);
            bv[m] = *(const bfx8*)(sB + boff[m]);
        }
        #pragma unroll
        for (int m = 0; m < 4; ++m)
            #pragma unroll
            for (int n = 0; n < 4; ++n)
                acc[m][n] = __builtin_amdgcn_mfma_f32_16x16x32_bf16(av[m], bv[n], acc[m][n], 0, 0, 0);
        __syncthreads();
    }

    #pragma unroll
    for (int m = 0; m < 4; ++m) {
        #pragma unroll
        for (int n = 0; n < 4; ++n) {
            const int col = bn + wc * 64 + n * 16 + lrow;
            float bv2 = (EPI >= 1) ? bias[col] : 0.f;
            #pragma unroll
            for (int e = 0; e < 4; ++e) {
                const int row = bm + wr * 64 + m * 16 + lgr * 4 + e;
                if (row < M) {
                    float v = acc[m][n][e] + bv2;
                    if (EPI == 2) v = gelu_f(v);
                    if (EPI == 3) v += resid[(size_t)row * N + col];
                    C[(size_t)row * N + col] = (OT)v;
                }
            }
        }
    }
}

// ---------------------------------------------------------------------------
// MFMA fused attention. Block = (h, b), 4 waves, 16x16x32 bf16 MFMA.
// Tokens padded to 224 (13 S n-tiles of 16; 7 PV k-steps of 32).
// K: LDS [224 rows][128B] xor-chunk-swizzled (verified mgemm B pattern).
// V: staged TRANSPOSED in LDS, VT[64 d-rows][stride 464B] over tokens; pad
//    tokens zeroed. PV B-frag = plain contiguous b128 (mgemm pattern).
// P: per-wave LDS [16 rows][stride 464B]; explicit lgkmcnt fence between
//    cross-lane P write and PV read (compiler may not order them itself).
// Q A-frags straight from global (L2-resident).
// ---------------------------------------------------------------------------
__global__ __launch_bounds__(256) void attn_k(const __hip_bfloat16* __restrict__ Q,
                                              const __hip_bfloat16* __restrict__ K,
                                              const __hip_bfloat16* __restrict__ V,
                                              __hip_bfloat16* __restrict__ O) {
    __shared__ __align__(16) char Ks[224 * 128];   // 28672
    __shared__ __align__(16) char VTs[64 * 464];   // 29696
    __shared__ __align__(16) char Ps[4][7424];     // 4 x (16 rows x 464B)

    const int h = blockIdx.x;
    const int b = blockIdx.y;
    const int t = threadIdx.x;
    const int lane = t & 63, w = t >> 6;
    const int rho = lane & 15, g = lane >> 4;
    const size_t base = ((size_t)b * NTOK) * 768 + h * 64;

    // ---- stage K (xor source pre-swizzle; LDS dst lane-linear for gload) ----
    #pragma unroll
    for (int i = 0; i < 7; ++i) {
        int q = t + i * 256;            // 0..1791
        int j = q >> 3, c = q & 7;
        int gc = c ^ (j & 7);
        GLOAD16(K + base + (size_t)j * 768 + gc * 8, Ks + q * 16);
    }
    // ---- stage V transposed: VT[d][tok] (reg-staged; pad tokens zeroed) ----
    #pragma unroll
    for (int i = 0; i < 7; ++i) {
        int q = t + i * 256;
        int tok = q >> 3, c = q & 7;    // thread holds V[tok][c*8 .. c*8+7]
        bfx8 vv = {0, 0, 0, 0, 0, 0, 0, 0};
        if (tok < NTOK) vv = *(const bfx8*)(V + base + (size_t)tok * 768 + c * 8);
        #pragma unroll
        for (int u = 0; u < 8; ++u)
            *(unsigned short*)(VTs + (c * 8 + u) * 464 + tok * 2) = (unsigned short)vv[u];
    }
    __syncthreads();

    char* Pw = Ps[w];

    for (int qt = w; qt < 13; qt += 4) {
        const int q0 = qt * 16;
        // ---- S = Q K^T ----
        fx4 s[13];
        #pragma unroll
        for (int nt = 0; nt < 13; ++nt)
            #pragma unroll
            for (int e = 0; e < 4; ++e) s[nt][e] = 0.f;
        #pragma unroll
        for (int ks = 0; ks < 2; ++ks) {
            bfx8 av = *(const bfx8*)(Q + base + (size_t)(q0 + rho) * 768 + ks * 32 + g * 8);
            #pragma unroll
            for (int nt = 0; nt < 13; ++nt) {
                int r = nt * 16 + rho;
                bfx8 bv = *(const bfx8*)(Ks + r * 128 + (((ks * 4 + g) ^ (r & 7)) << 4));
                s[nt] = __builtin_amdgcn_mfma_f32_16x16x32_bf16(av, bv, s[nt], 0, 0, 0);
            }
        }
        // ---- softmax over cols (tokens); row = g*4+e, token = nt*16+rho ----
        float mx[4] = {-1e30f, -1e30f, -1e30f, -1e30f};
        #pragma unroll
        for (int nt = 0; nt < 13; ++nt) {
            #pragma unroll
            for (int e = 0; e < 4; ++e) {
                float v = s[nt][e] * 0.125f;
                if (nt == 12 && rho >= 5) v = -1e30f;
                s[nt][e] = v;
                mx[e] = fmaxf(mx[e], v);
            }
        }
        #pragma unroll
        for (int off = 1; off < 16; off <<= 1)
            #pragma unroll
            for (int e = 0; e < 4; ++e) mx[e] = fmaxf(mx[e], __shfl_xor(mx[e], off));
        float sm[4] = {0.f, 0.f, 0.f, 0.f};
        #pragma unroll
        for (int nt = 0; nt < 13; ++nt)
            #pragma unroll
            for (int e = 0; e < 4; ++e) {
                float p = __expf(s[nt][e] - mx[e]);
                s[nt][e] = p;
                sm[e] += p;
            }
        #pragma unroll
        for (int off = 1; off < 16; off <<= 1)
            #pragma unroll
            for (int e = 0; e < 4; ++e) sm[e] += __shfl_xor(sm[e], off);
        float inv[4];
        #pragma unroll
        for (int e = 0; e < 4; ++e) inv[e] = 1.0f / sm[e];

        // ---- write P (bf16) to per-wave LDS: P[qrow_local][token] ----
        #pragma unroll
        for (int nt = 0; nt < 13; ++nt)
            #pragma unroll
            for (int e = 0; e < 4; ++e) {
                int row = g * 4 + e;
                int col = nt * 16 + rho;
                *(__hip_bfloat16*)(Pw + row * 464 + col * 2) =
                    (__hip_bfloat16)(s[nt][e] * inv[e]);
            }
        #pragma unroll
        for (int e = 0; e < 4; ++e)
            *(__hip_bfloat16*)(Pw + (g * 4 + e) * 464 + (208 + rho) * 2) = (__hip_bfloat16)0.0f;

        // fence: cross-lane P write -> read (order + completion, wave-local)
        __builtin_amdgcn_sched_barrier(0);
        asm volatile("s_waitcnt lgkmcnt(0)" ::: "memory");
        __builtin_amdgcn_sched_barrier(0);

        // ---- O = P V : A = P[16 x 224], B = VT rows (d), K = tokens ----
        #pragma unroll
        for (int dt = 0; dt < 4; ++dt) {
            fx4 o;
            #pragma unroll
            for (int e = 0; e < 4; ++e) o[e] = 0.f;
            #pragma unroll
            for (int ks = 0; ks < 7; ++ks) {
                bfx8 pa = *(const bfx8*)(Pw + rho * 464 + (ks * 4 + g) * 16);
                bfx8 bv = *(const bfx8*)(VTs + (dt * 16 + rho) * 464 + (ks * 4 + g) * 16);
                o = __builtin_amdgcn_mfma_f32_16x16x32_bf16(pa, bv, o, 0, 0, 0);
            }
            #pragma unroll
            for (int e = 0; e < 4; ++e) {
                int qrow = q0 + g * 4 + e;
                if (qrow < NTOK)
                    O[base + (size_t)qrow * 768 + dt * 16 + rho] = (__hip_bfloat16)o[e];
            }
        }
    }
}

// ---------------------------------------------------------------------------
// Head: logits = z_ln[b,0,:] @ W_head + b_head ; softmax -> out[b,1000]
// ---------------------------------------------------------------------------
__global__ __launch_bounds__(256) void head_k(const float* __restrict__ xa,
                                              const float* __restrict__ Wh,
                                              const float* __restrict__ bh,
                                              float* __restrict__ out) {
    const int b = blockIdx.x;
    const int t = threadIdx.x;
    __shared__ float zr[768];
    __shared__ float lg[1000];
    __shared__ float red[4];

    for (int d = t; d < 768; d += 256) zr[d] = xa[((size_t)b * 197) * 768 + d];
    __syncthreads();

    for (int c = t; c < 1000; c += 256) {
        float acc = bh[c];
        #pragma unroll 8
        for (int k = 0; k < 768; ++k) acc += zr[k] * Wh[(size_t)k * 1000 + c];
        lg[c] = acc;
    }
    __syncthreads();

    float m = -1e30f;
    for (int c = t; c < 1000; c += 256) m = fmaxf(m, lg[c]);
    #pragma unroll
    for (int off = 32; off; off >>= 1) m = fmaxf(m, __shfl_xor(m, off));
    if ((t & 63) == 0) red[t >> 6] = m;
    __syncthreads();
    m = fmaxf(fmaxf(red[0], red[1]), fmaxf(red[2], red[3]));
    __syncthreads();

    float sum = 0.f;
    for (int c = t; c < 1000; c += 256) sum += __expf(lg[c] - m);
    #pragma unroll
    for (int off = 32; off; off >>= 1) sum += __shfl_xor(sum, off);
    if ((t & 63) == 0) red[t >> 6] = sum;
    __syncthreads();
    sum = red[0] + red[1] + red[2] + red[3];
    const float invs = 1.0f / sum;
    for (int c = t; c < 1000; c += 256) out[(size_t)b * 1000 + c] = __expf(lg[c] - m) * invs;
}

// ---------------------------------------------------------------------------
// Driver
// ---------------------------------------------------------------------------
extern "C" void kernel_launch(void* const* d_in, const int* in_sizes, int n_in,
                              void* d_out, int out_size, void* d_ws, size_t ws_size,
                              hipStream_t stream) {
    const float* x        = (const float*)d_in[0];
    const float* ln_p_g   = (const float*)d_in[1];
    const float* ln_p_b   = (const float*)d_in[2];
    const float* W_patch  = (const float*)d_in[3];
    const float* b_patch  = (const float*)d_in[4];
    const float* ln_e_g   = (const float*)d_in[5];
    const float* ln_e_b   = (const float*)d_in[6];
    const float* pos_emb  = (const float*)d_in[7];
    const float* cls_tok  = (const float*)d_in[8];
    const float* ln_a_g   = (const float*)d_in[9];
    const float* ln_a_b   = (const float*)d_in[10];
    const float* Wq       = (const float*)d_in[11];
    const float* Wk       = (const float*)d_in[12];
    const float* Wv       = (const float*)d_in[13];
    const float* Wo       = (const float*)d_in[14];
    const float* bo       = (const float*)d_in[15];
    const float* ln_f_g   = (const float*)d_in[16];
    const float* ln_f_b   = (const float*)d_in[17];
    const float* W1       = (const float*)d_in[18];
    const float* b1       = (const float*)d_in[19];
    const float* W2       = (const float*)d_in[20];
    const float* b2       = (const float*)d_in[21];
    const float* ln_out_g = (const float*)d_in[22];
    const float* ln_out_b = (const float*)d_in[23];
    const float* W_head   = (const float*)d_in[24];
    const float* b_head   = (const float*)d_in[25];

    typedef __hip_bfloat16 bf;
    const int M  = 12608;               // 64*197
    const int MP = 12672;               // padded to 99*128
    char* p = (char*)d_ws;

    float* Z   = (float*)p;            p += (size_t)MP * 768 * 4;      // fp32 residual
    bf* XA     = (bf*)p;               p += (size_t)MP * 768 * 2;      // LN out (bf16)
    bf* QB     = (bf*)p;               p += (size_t)MP * 768 * 2;
    bf* KB     = (bf*)p;               p += (size_t)MP * 768 * 2;
    bf* VB     = (bf*)p;               p += (size_t)MP * 768 * 2;
    bf* OB     = (bf*)p;               p += (size_t)MP * 768 * 2;
    char* FFHc = p;                    p += (size_t)MP * 3072 * 2;     // bf16 GELU buf
    bf* FFH    = (bf*)FFHc;
    float* PE  = (float*)FFHc;                                          // alias: patch-embed fp32
    float* E2  = (float*)(FFHc + (size_t)MP * 768 * 4);                 // alias: ln_e out fp32
    float* FLN = (float*)FFHc;                                          // alias: final LN fp32
    bf* WqT    = (bf*)p;               p += (size_t)12 * 768 * 768 * 2;
    bf* WkT    = (bf*)p;               p += (size_t)12 * 768 * 768 * 2;
    bf* WvT    = (bf*)p;               p += (size_t)12 * 768 * 768 * 2;
    bf* WoT    = (bf*)p;               p += (size_t)12 * 768 * 768 * 2;
    bf* W1T    = (bf*)p;               p += (size_t)12 * 3072 * 768 * 2;
    bf* W2T    = (bf*)p;               p += (size_t)12 * 768 * 3072 * 2;
    bf* WpT    = (bf*)p;               p += (size_t)768 * 768 * 2;

    // weight convert + transpose (every launch; ~510 MB traffic)
    wconv_k<<<dim3(12, 12, 12), 256, 0, stream>>>(Wq, WqT, 768, 768);
    wconv_k<<<dim3(12, 12, 12), 256, 0, stream>>>(Wk, WkT, 768, 768);
    wconv_k<<<dim3(12, 12, 12), 256, 0, stream>>>(Wv, WvT, 768, 768);
    wconv_k<<<dim3(12, 12, 12), 256, 0, stream>>>(Wo, WoT, 768, 768);
    wconv_k<<<dim3(48, 12, 12), 256, 0, stream>>>(W1, W1T, 768, 3072);
    wconv_k<<<dim3(12, 48, 12), 256, 0, stream>>>(W2, W2T, 3072, 768);
    wconv_k<<<dim3(12, 12, 1),  256, 0, stream>>>(W_patch, WpT, 768, 768);

    // patch embed pipeline
    patch_ln_k<<<12544, 256, 0, stream>>>(x, XA, ln_p_g, ln_p_b);
    mgemm_k<1, float><<<dim3(6, 98), 256, 0, stream>>>(XA, WpT, b_patch, nullptr, PE, 12544, 768, 768);
    ln_k<float><<<12544, 256, 0, stream>>>(PE, E2, ln_e_g, ln_e_b);
    build_z_k<<<37824, 256, 0, stream>>>(E2, cls_tok, pos_emb, Z);

    for (int i = 0; i < 12; ++i) {
        bf* WqT_i = WqT + (size_t)i * 768 * 768;
        bf* WkT_i = WkT + (size_t)i * 768 * 768;
        bf* WvT_i = WvT + (size_t)i * 768 * 768;
        bf* WoT_i = WoT + (size_t)i * 768 * 768;
        bf* W1T_i = W1T + (size_t)i * 3072 * 768;
        bf* W2T_i = W2T + (size_t)i * 768 * 3072;

        ln_k<bf><<<M, 256, 0, stream>>>(Z, XA, ln_a_g + (size_t)i * 768, ln_a_b + (size_t)i * 768);
        mgemm_k<0, bf><<<dim3(6, 99), 256, 0, stream>>>(XA, WqT_i, nullptr, nullptr, QB, M, 768, 768);
        mgemm_k<0, bf><<<dim3(6, 99), 256, 0, stream>>>(XA, WkT_i, nullptr, nullptr, KB, M, 768, 768);
        mgemm_k<0, bf><<<dim3(6, 99), 256, 0, stream>>>(XA, WvT_i, nullptr, nullptr, VB, M, 768, 768);
        attn_k<<<dim3(12, 64), 256, 0, stream>>>(QB, KB, VB, OB);
        mgemm_k<3, float><<<dim3(6, 99), 256, 0, stream>>>(OB, WoT_i, bo + (size_t)i * 768, Z, Z, M, 768, 768);
        ln_k<bf><<<M, 256, 0, stream>>>(Z, XA, ln_f_g + (size_t)i * 768, ln_f_b + (size_t)i * 768);
        mgemm_k<2, bf><<<dim3(24, 99), 256, 0, stream>>>(XA, W1T_i, b1 + (size_t)i * 3072, nullptr, FFH, M, 3072, 768);
        mgemm_k<3, float><<<dim3(6, 99), 256, 0, stream>>>(FFH, W2T_i, b2 + (size_t)i * 768, Z, Z, M, 768, 3072);
    }

    ln_k<float><<<M, 256, 0, stream>>>(Z, FLN, ln_out_g, ln_out_b);
    head_k<<<64, 256, 0, stream>>>(FLN, W_head, b_head, (float*)d_out);
}

// Round 5
// 5037.642 us; speedup vs baseline: 9.7262x; 1.2272x over previous
//
#include <hip/hip_runtime.h>
#include <hip/hip_bf16.h>
#include <math.h>

#define NTOK 197

typedef __attribute__((ext_vector_type(8))) short bfx8;
typedef __attribute__((ext_vector_type(4))) float fx4;

#define GLOAD16(gsrc, ldst) __builtin_amdgcn_global_load_lds( \
    (const __attribute__((address_space(1))) void*)(gsrc),    \
    (__attribute__((address_space(3))) void*)(ldst), 16, 0, 0)

__device__ __forceinline__ float gelu_f(float x) {
    return 0.5f * x * (1.0f + erff(x * 0.70710678118654752f));
}

// ---------------------------------------------------------------------------
// Patch extraction + LayerNorm -> bf16. Coalesced float4 loads staged via LDS.
// ---------------------------------------------------------------------------
__global__ __launch_bounds__(256) void patch_ln_k(const float* __restrict__ x,
                                                  __hip_bfloat16* __restrict__ out,
                                                  const float* __restrict__ g,
                                                  const float* __restrict__ bt) {
    const int r = blockIdx.x;          // 0..12543
    const int t = threadIdx.x;
    const int b = r / 196, p = r % 196;
    const int ph = p / 14, pw = p % 14;

    __shared__ float px[768];
    if (t < 192) {
        int rr = t >> 2, seg = t & 3;
        int c = rr >> 4, h1 = rr & 15;
        const float* src = x + (((size_t)b * 3 + c) * 224 + (ph * 16 + h1)) * 224
                             + pw * 16 + seg * 4;
        float4 v4 = *(const float4*)src;
        px[(h1 * 16 + seg * 4 + 0) * 3 + c] = v4.x;
        px[(h1 * 16 + seg * 4 + 1) * 3 + c] = v4.y;
        px[(h1 * 16 + seg * 4 + 2) * 3 + c] = v4.z;
        px[(h1 * 16 + seg * 4 + 3) * 3 + c] = v4.w;
    }
    __syncthreads();

    float v[3];
    #pragma unroll
    for (int i = 0; i < 3; ++i) v[i] = px[t + i * 256];
    float s = v[0] + v[1] + v[2];
    float sq = v[0]*v[0] + v[1]*v[1] + v[2]*v[2];
    #pragma unroll
    for (int off = 32; off; off >>= 1) { s += __shfl_xor(s, off); sq += __shfl_xor(sq, off); }
    __shared__ float ss[4], s2[4];
    const int w = t >> 6;
    if ((t & 63) == 0) { ss[w] = s; s2[w] = sq; }
    __syncthreads();
    s  = ss[0] + ss[1] + ss[2] + ss[3];
    sq = s2[0] + s2[1] + s2[2] + s2[3];
    const float inv = 1.0f / 768.0f;
    float mu = s * inv;
    float var = sq * inv - mu * mu;
    float rstd = rsqrtf(var + 1e-5f);
    __hip_bfloat16* o = out + (size_t)r * 768;
    #pragma unroll
    for (int i = 0; i < 3; ++i) {
        int d = t + i * 256;
        o[d] = (__hip_bfloat16)((v[i] - mu) * rstd * g[d] + bt[d]);
    }
}

// ---------------------------------------------------------------------------
// Row LayerNorm over 768 fp32 -> OT
// ---------------------------------------------------------------------------
template <typename OT>
__global__ __launch_bounds__(256) void ln_k(const float* __restrict__ in,
                                            OT* __restrict__ out,
                                            const float* __restrict__ g,
                                            const float* __restrict__ bt) {
    const int r = blockIdx.x;
    const int t = threadIdx.x;
    const float* xr = in + (size_t)r * 768;
    float v0 = xr[t], v1 = xr[t + 256], v2 = xr[t + 512];
    float s = v0 + v1 + v2;
    float sq = v0*v0 + v1*v1 + v2*v2;
    #pragma unroll
    for (int off = 32; off; off >>= 1) { s += __shfl_xor(s, off); sq += __shfl_xor(sq, off); }
    __shared__ float ss[4], s2[4];
    const int w = t >> 6;
    if ((t & 63) == 0) { ss[w] = s; s2[w] = sq; }
    __syncthreads();
    s  = ss[0] + ss[1] + ss[2] + ss[3];
    sq = s2[0] + s2[1] + s2[2] + s2[3];
    const float inv = 1.0f / 768.0f;
    float mu = s * inv;
    float var = sq * inv - mu * mu;
    float rstd = rsqrtf(var + 1e-5f);
    OT* o = out + (size_t)r * 768;
    o[t]       = (OT)((v0 - mu) * rstd * g[t]       + bt[t]);
    o[t + 256] = (OT)((v1 - mu) * rstd * g[t + 256] + bt[t + 256]);
    o[t + 512] = (OT)((v2 - mu) * rstd * g[t + 512] + bt[t + 512]);
}

// ---------------------------------------------------------------------------
// LN of CLS rows only -> bf16 [128][768] (rows 64..127 zeroed)
// ---------------------------------------------------------------------------
__global__ __launch_bounds__(256) void ln_cls_k(const float* __restrict__ in,
                                                __hip_bfloat16* __restrict__ out,
                                                const float* __restrict__ g,
                                                const float* __restrict__ bt) {
    const int b = blockIdx.x;   // 0..127
    const int t = threadIdx.x;
    if (b >= 64) {
        #pragma unroll
        for (int i = 0; i < 3; ++i) out[(size_t)b * 768 + t + i * 256] = (__hip_bfloat16)0.0f;
        return;
    }
    const float* xr = in + (size_t)b * 197 * 768;
    float v0 = xr[t], v1 = xr[t + 256], v2 = xr[t + 512];
    float s = v0 + v1 + v2;
    float sq = v0*v0 + v1*v1 + v2*v2;
    #pragma unroll
    for (int off = 32; off; off >>= 1) { s += __shfl_xor(s, off); sq += __shfl_xor(sq, off); }
    __shared__ float ss[4], s2[4];
    const int w = t >> 6;
    if ((t & 63) == 0) { ss[w] = s; s2[w] = sq; }
    __syncthreads();
    s  = ss[0] + ss[1] + ss[2] + ss[3];
    sq = s2[0] + s2[1] + s2[2] + s2[3];
    const float inv = 1.0f / 768.0f;
    float mu = s * inv;
    float var = sq * inv - mu * mu;
    float rstd = rsqrtf(var + 1e-5f);
    __hip_bfloat16* o = out + (size_t)b * 768;
    o[t]       = (__hip_bfloat16)((v0 - mu) * rstd * g[t]       + bt[t]);
    o[t + 256] = (__hip_bfloat16)((v1 - mu) * rstd * g[t + 256] + bt[t + 256]);
    o[t + 512] = (__hip_bfloat16)((v2 - mu) * rstd * g[t + 512] + bt[t + 512]);
}

// ---------------------------------------------------------------------------
// z = concat(cls, p_ln) + pos  -> [64,197,768] fp32
// ---------------------------------------------------------------------------
__global__ __launch_bounds__(256) void build_z_k(const float* __restrict__ pln,
                                                 const float* __restrict__ cls,
                                                 const float* __restrict__ pos,
                                                 float* __restrict__ z) {
    size_t idx = (size_t)blockIdx.x * 256 + threadIdx.x;
    int d  = idx % 768;
    size_t tkb = idx / 768;
    int tk = tkb % 197;
    int b  = tkb / 197;
    float v = (tk == 0) ? cls[d] : pln[((size_t)b * 196 + (tk - 1)) * 768 + d];
    z[idx] = v + pos[(size_t)tk * 768 + d];
}

// ---------------------------------------------------------------------------
// Weight convert + transpose: fp32 [K,N] -> bf16 [N,K], z-strided output
// ---------------------------------------------------------------------------
__global__ __launch_bounds__(256) void wconv_k(const float* __restrict__ W,
                                               __hip_bfloat16* __restrict__ Wt,
                                               int K, int N, size_t ostride) {
    __shared__ float tl[64][65];
    const int t = threadIdx.x;
    const int n0 = blockIdx.x * 64, k0 = blockIdx.y * 64;
    const size_t ibase = (size_t)blockIdx.z * K * N;
    const size_t obase = (size_t)blockIdx.z * ostride;
    #pragma unroll
    for (int i = 0; i < 16; ++i) {
        int idx = i * 256 + t;
        int kl = idx >> 6, nl = idx & 63;
        tl[kl][nl] = W[ibase + (size_t)(k0 + kl) * N + n0 + nl];
    }
    __syncthreads();
    #pragma unroll
    for (int i = 0; i < 16; ++i) {
        int idx = i * 256 + t;
        int nl = idx >> 6, kl = idx & 63;
        Wt[obase + (size_t)(n0 + nl) * K + k0 + kl] = (__hip_bfloat16)tl[kl][nl];
    }
}

// ---------------------------------------------------------------------------
// W_head transpose: fp32 [768][1000] -> bf16 [1024][768], pad rows zeroed
// ---------------------------------------------------------------------------
__global__ __launch_bounds__(256) void whT_k(const float* __restrict__ W,
                                             __hip_bfloat16* __restrict__ Wt) {
    __shared__ float tl[64][65];
    const int t = threadIdx.x;
    const int n0 = blockIdx.x * 64, k0 = blockIdx.y * 64;
    #pragma unroll
    for (int i = 0; i < 16; ++i) {
        int idx = i * 256 + t;
        int kl = idx >> 6, nl = idx & 63;
        int n = n0 + nl;
        tl[kl][nl] = (n < 1000) ? W[(size_t)(k0 + kl) * 1000 + n] : 0.f;
    }
    __syncthreads();
    #pragma unroll
    for (int i = 0; i < 16; ++i) {
        int idx = i * 256 + t;
        int nl = idx >> 6, kl = idx & 63;
        Wt[(size_t)(n0 + nl) * 768 + k0 + kl] = (__hip_bfloat16)tl[kl][nl];
    }
}

// ---------------------------------------------------------------------------
// bf16 MFMA GEMM, BK=64 (2 K-substeps per barrier pair).
// C = A[M,K](bf16) @ Wt[N,K]^T (+epilogue). N%128==0, K%64==0, A padded rows.
// LDS [128 rows][8 slots of 16B]; slot = chunk ^ (row&7) (<=2-way alias).
// EPI: 0 none, 1 +bias, 2 +bias+gelu, 3 +bias+residual.
// ---------------------------------------------------------------------------
template <int EPI, typename OT>
__global__ __launch_bounds__(256) void mgemm_k(const __hip_bfloat16* __restrict__ A,
                                               const __hip_bfloat16* __restrict__ Wt,
                                               const float* __restrict__ bias,
                                               const float* __restrict__ resid,
                                               OT* __restrict__ C,
                                               int M, int N, int K) {
    __shared__ __align__(16) char sA[16384];
    __shared__ __align__(16) char sB[16384];
    const int t = threadIdx.x;
    const int lane = t & 63, w = t >> 6;
    const int wr = w >> 1, wc = w & 1;
    const int lrow = lane & 15, lgr = lane >> 4;
    const int bm = blockIdx.y * 128, bn = blockIdx.x * 128;

    const __hip_bfloat16* aSrc[4];
    const __hip_bfloat16* bSrc[4];
    #pragma unroll
    for (int i = 0; i < 4; ++i) {
        int q = t + i * 256;          // 0..1023
        int r = q >> 3, c = q & 7;
        int gc = c ^ (r & 7);
        aSrc[i] = A  + (size_t)(bm + r) * K + gc * 8;
        bSrc[i] = Wt + (size_t)(bn + r) * K + gc * 8;
    }

    int aoff[4][2], boff[4][2];
    #pragma unroll
    for (int m = 0; m < 4; ++m) {
        int ra = wr * 64 + m * 16 + lrow;
        int rb = wc * 64 + m * 16 + lrow;
        #pragma unroll
        for (int ks = 0; ks < 2; ++ks) {
            aoff[m][ks] = ra * 128 + (((ks * 4 + lgr) ^ (ra & 7)) << 4);
            boff[m][ks] = rb * 128 + (((ks * 4 + lgr) ^ (rb & 7)) << 4);
        }
    }

    fx4 acc[4][4];
    #pragma unroll
    for (int m = 0; m < 4; ++m)
        #pragma unroll
        for (int n = 0; n < 4; ++n)
            #pragma unroll
            for (int e = 0; e < 4; ++e) acc[m][n][e] = 0.f;

    for (int k0 = 0; k0 < K; k0 += 64) {
        #pragma unroll
        for (int i = 0; i < 4; ++i) GLOAD16(aSrc[i] + k0, sA + (t + i * 256) * 16);
        #pragma unroll
        for (int i = 0; i < 4; ++i) GLOAD16(bSrc[i] + k0, sB + (t + i * 256) * 16);
        __syncthreads();
        #pragma unroll
        for (int ks = 0; ks < 2; ++ks) {
            bfx8 av[4], bv[4];
            #pragma unroll
            for (int m = 0; m < 4; ++m) {
                av[m] = *(const bfx8*)(sA + aoff[m][ks]);
                bv[m] = *(const bfx8*)(sB + boff[m][ks]);
            }
            #pragma unroll
            for (int m = 0; m < 4; ++m)
                #pragma unroll
                for (int n = 0; n < 4; ++n)
                    acc[m][n] = __builtin_amdgcn_mfma_f32_16x16x32_bf16(av[m], bv[n], acc[m][n], 0, 0, 0);
        }
        __syncthreads();
    }

    #pragma unroll
    for (int m = 0; m < 4; ++m) {
        #pragma unroll
        for (int n = 0; n < 4; ++n) {
            const int col = bn + wc * 64 + n * 16 + lrow;
            float bv2 = (EPI >= 1) ? bias[col] : 0.f;
            #pragma unroll
            for (int e = 0; e < 4; ++e) {
                const int row = bm + wr * 64 + m * 16 + lgr * 4 + e;
                if (row < M) {
                    float v = acc[m][n][e] + bv2;
                    if (EPI == 2) v = gelu_f(v);
                    if (EPI == 3) v += resid[(size_t)row * N + col];
                    C[(size_t)row * N + col] = (OT)v;
                }
            }
        }
    }
}

// ---------------------------------------------------------------------------
// MFMA fused attention on fused QKV buffer (row stride 2304).
// Q cols h*64.. ; K cols 768+h*64.. ; V cols 1536+h*64..
// ---------------------------------------------------------------------------
__global__ __launch_bounds__(256) void attn_k(const __hip_bfloat16* __restrict__ QKV,
                                              __hip_bfloat16* __restrict__ O) {
    __shared__ __align__(16) char Ks[224 * 128];   // 28672
    __shared__ __align__(16) char VTs[64 * 464];   // 29696
    __shared__ __align__(16) char Ps[4][7424];     // 4 x (16 rows x 464B)

    const int h = blockIdx.x;
    const int b = blockIdx.y;
    const int t = threadIdx.x;
    const int lane = t & 63, w = t >> 6;
    const int rho = lane & 15, g = lane >> 4;
    const size_t base = (size_t)b * NTOK * 2304;
    const int qoff = h * 64, koff = 768 + h * 64, voff = 1536 + h * 64;
    const size_t obase = ((size_t)b * NTOK) * 768 + h * 64;

    // ---- stage K (xor source pre-swizzle; LDS dst lane-linear for gload) ----
    #pragma unroll
    for (int i = 0; i < 7; ++i) {
        int q = t + i * 256;            // 0..1791
        int j = q >> 3, c = q & 7;
        int gc = c ^ (j & 7);
        GLOAD16(QKV + base + (size_t)j * 2304 + koff + gc * 8, Ks + q * 16);
    }
    // ---- stage V transposed: VT[d][tok] (reg-staged; pad tokens zeroed) ----
    #pragma unroll
    for (int i = 0; i < 7; ++i) {
        int q = t + i * 256;
        int tok = q >> 3, c = q & 7;
        bfx8 vv = {0, 0, 0, 0, 0, 0, 0, 0};
        if (tok < NTOK) vv = *(const bfx8*)(QKV + base + (size_t)tok * 2304 + voff + c * 8);
        #pragma unroll
        for (int u = 0; u < 8; ++u)
            *(unsigned short*)(VTs + (c * 8 + u) * 464 + tok * 2) = (unsigned short)vv[u];
    }
    __syncthreads();

    char* Pw = Ps[w];

    for (int qt = w; qt < 13; qt += 4) {
        const int q0 = qt * 16;
        // ---- S = Q K^T ----
        fx4 s[13];
        #pragma unroll
        for (int nt = 0; nt < 13; ++nt)
            #pragma unroll
            for (int e = 0; e < 4; ++e) s[nt][e] = 0.f;
        #pragma unroll
        for (int ks = 0; ks < 2; ++ks) {
            bfx8 av = *(const bfx8*)(QKV + base + (size_t)(q0 + rho) * 2304 + qoff + ks * 32 + g * 8);
            #pragma unroll
            for (int nt = 0; nt < 13; ++nt) {
                int r = nt * 16 + rho;
                bfx8 bv = *(const bfx8*)(Ks + r * 128 + (((ks * 4 + g) ^ (r & 7)) << 4));
                s[nt] = __builtin_amdgcn_mfma_f32_16x16x32_bf16(av, bv, s[nt], 0, 0, 0);
            }
        }
        // ---- softmax over cols (tokens); row = g*4+e, token = nt*16+rho ----
        float mx[4] = {-1e30f, -1e30f, -1e30f, -1e30f};
        #pragma unroll
        for (int nt = 0; nt < 13; ++nt) {
            #pragma unroll
            for (int e = 0; e < 4; ++e) {
                float v = s[nt][e] * 0.125f;
                if (nt == 12 && rho >= 5) v = -1e30f;
                s[nt][e] = v;
                mx[e] = fmaxf(mx[e], v);
            }
        }
        #pragma unroll
        for (int off = 1; off < 16; off <<= 1)
            #pragma unroll
            for (int e = 0; e < 4; ++e) mx[e] = fmaxf(mx[e], __shfl_xor(mx[e], off));
        float sm[4] = {0.f, 0.f, 0.f, 0.f};
        #pragma unroll
        for (int nt = 0; nt < 13; ++nt)
            #pragma unroll
            for (int e = 0; e < 4; ++e) {
                float p = __expf(s[nt][e] - mx[e]);
                s[nt][e] = p;
                sm[e] += p;
            }
        #pragma unroll
        for (int off = 1; off < 16; off <<= 1)
            #pragma unroll
            for (int e = 0; e < 4; ++e) sm[e] += __shfl_xor(sm[e], off);
        float inv[4];
        #pragma unroll
        for (int e = 0; e < 4; ++e) inv[e] = 1.0f / sm[e];

        // ---- write P (bf16) to per-wave LDS: P[qrow_local][token] ----
        #pragma unroll
        for (int nt = 0; nt < 13; ++nt)
            #pragma unroll
            for (int e = 0; e < 4; ++e) {
                int row = g * 4 + e;
                int col = nt * 16 + rho;
                *(__hip_bfloat16*)(Pw + row * 464 + col * 2) =
                    (__hip_bfloat16)(s[nt][e] * inv[e]);
            }
        #pragma unroll
        for (int e = 0; e < 4; ++e)
            *(__hip_bfloat16*)(Pw + (g * 4 + e) * 464 + (208 + rho) * 2) = (__hip_bfloat16)0.0f;

        // fence: cross-lane P write -> read (order + completion, wave-local)
        __builtin_amdgcn_sched_barrier(0);
        asm volatile("s_waitcnt lgkmcnt(0)" ::: "memory");
        __builtin_amdgcn_sched_barrier(0);

        // ---- O = P V : A = P[16 x 224], B = VT rows (d), K = tokens ----
        #pragma unroll
        for (int dt = 0; dt < 4; ++dt) {
            fx4 o;
            #pragma unroll
            for (int e = 0; e < 4; ++e) o[e] = 0.f;
            #pragma unroll
            for (int ks = 0; ks < 7; ++ks) {
                bfx8 pa = *(const bfx8*)(Pw + rho * 464 + (ks * 4 + g) * 16);
                bfx8 bv = *(const bfx8*)(VTs + (dt * 16 + rho) * 464 + (ks * 4 + g) * 16);
                o = __builtin_amdgcn_mfma_f32_16x16x32_bf16(pa, bv, o, 0, 0, 0);
            }
            #pragma unroll
            for (int e = 0; e < 4; ++e) {
                int qrow = q0 + g * 4 + e;
                if (qrow < NTOK)
                    O[obase + (size_t)qrow * 768 + dt * 16 + rho] = (__hip_bfloat16)o[e];
            }
        }
    }
}

// ---------------------------------------------------------------------------
// Head softmax: out[b,:] = softmax(logits[b,:1000] + b_head)
// ---------------------------------------------------------------------------
__global__ __launch_bounds__(256) void shead_k(const float* __restrict__ logits,
                                               const float* __restrict__ bh,
                                               float* __restrict__ out) {
    const int b = blockIdx.x;
    const int t = threadIdx.x;
    __shared__ float lg[1000];
    __shared__ float red[4];

    for (int c = t; c < 1000; c += 256) lg[c] = logits[(size_t)b * 1024 + c] + bh[c];
    __syncthreads();

    float m = -1e30f;
    for (int c = t; c < 1000; c += 256) m = fmaxf(m, lg[c]);
    #pragma unroll
    for (int off = 32; off; off >>= 1) m = fmaxf(m, __shfl_xor(m, off));
    if ((t & 63) == 0) red[t >> 6] = m;
    __syncthreads();
    m = fmaxf(fmaxf(red[0], red[1]), fmaxf(red[2], red[3]));
    __syncthreads();

    float sum = 0.f;
    for (int c = t; c < 1000; c += 256) sum += __expf(lg[c] - m);
    #pragma unroll
    for (int off = 32; off; off >>= 1) sum += __shfl_xor(sum, off);
    if ((t & 63) == 0) red[t >> 6] = sum;
    __syncthreads();
    sum = red[0] + red[1] + red[2] + red[3];
    const float invs = 1.0f / sum;
    for (int c = t; c < 1000; c += 256) out[(size_t)b * 1000 + c] = __expf(lg[c] - m) * invs;
}

// ---------------------------------------------------------------------------
// Driver
// ---------------------------------------------------------------------------
extern "C" void kernel_launch(void* const* d_in, const int* in_sizes, int n_in,
                              void* d_out, int out_size, void* d_ws, size_t ws_size,
                              hipStream_t stream) {
    const float* x        = (const float*)d_in[0];
    const float* ln_p_g   = (const float*)d_in[1];
    const float* ln_p_b   = (const float*)d_in[2];
    const float* W_patch  = (const float*)d_in[3];
    const float* b_patch  = (const float*)d_in[4];
    const float* ln_e_g   = (const float*)d_in[5];
    const float* ln_e_b   = (const float*)d_in[6];
    const float* pos_emb  = (const float*)d_in[7];
    const float* cls_tok  = (const float*)d_in[8];
    const float* ln_a_g   = (const float*)d_in[9];
    const float* ln_a_b   = (const float*)d_in[10];
    const float* Wq       = (const float*)d_in[11];
    const float* Wk       = (const float*)d_in[12];
    const float* Wv       = (const float*)d_in[13];
    const float* Wo       = (const float*)d_in[14];
    const float* bo       = (const float*)d_in[15];
    const float* ln_f_g   = (const float*)d_in[16];
    const float* ln_f_b   = (const float*)d_in[17];
    const float* W1       = (const float*)d_in[18];
    const float* b1       = (const float*)d_in[19];
    const float* W2       = (const float*)d_in[20];
    const float* b2       = (const float*)d_in[21];
    const float* ln_out_g = (const float*)d_in[22];
    const float* ln_out_b = (const float*)d_in[23];
    const float* W_head   = (const float*)d_in[24];
    const float* b_head   = (const float*)d_in[25];

    typedef __hip_bfloat16 bf;
    const int M  = 12608;               // 64*197
    const int MP = 12672;               // padded to 99*128
    char* p = (char*)d_ws;

    float* Z   = (float*)p;            p += (size_t)MP * 768 * 4;      // fp32 residual
    bf* XA     = (bf*)p;               p += (size_t)MP * 768 * 2;      // LN out (bf16)
    bf* QKV    = (bf*)p;               p += (size_t)MP * 2304 * 2;     // fused q,k,v
    bf* OB     = (bf*)p;               p += (size_t)MP * 768 * 2;
    char* FFHc = p;                    p += (size_t)MP * 3072 * 2;     // bf16 GELU buf
    bf* FFH    = (bf*)FFHc;
    float* PE  = (float*)FFHc;                                          // alias: patch-embed fp32
    float* E2  = (float*)(FFHc + (size_t)MP * 768 * 4);                 // alias: ln_e out fp32
    bf* WQKVT  = (bf*)p;               p += (size_t)12 * 2304 * 768 * 2;
    bf* WoT    = (bf*)p;               p += (size_t)12 * 768 * 768 * 2;
    bf* W1T    = (bf*)p;               p += (size_t)12 * 3072 * 768 * 2;
    bf* W2T    = (bf*)p;               p += (size_t)12 * 768 * 3072 * 2;
    bf* WpT    = (bf*)p;               p += (size_t)768 * 768 * 2;
    bf* WhT    = (bf*)p;               p += (size_t)1024 * 768 * 2;
    bf* CLS    = (bf*)p;               p += (size_t)128 * 768 * 2;
    float* LOG = (float*)p;            p += (size_t)64 * 1024 * 4;

    const size_t QKVS = (size_t)2304 * 768;

    // weight convert + transpose (every launch)
    wconv_k<<<dim3(12, 12, 12), 256, 0, stream>>>(Wq, WQKVT,             768, 768,  QKVS);
    wconv_k<<<dim3(12, 12, 12), 256, 0, stream>>>(Wk, WQKVT + 768 * 768, 768, 768,  QKVS);
    wconv_k<<<dim3(12, 12, 12), 256, 0, stream>>>(Wv, WQKVT + 1536 * 768,768, 768,  QKVS);
    wconv_k<<<dim3(12, 12, 12), 256, 0, stream>>>(Wo, WoT,  768, 768,  (size_t)768 * 768);
    wconv_k<<<dim3(48, 12, 12), 256, 0, stream>>>(W1, W1T,  768, 3072, (size_t)3072 * 768);
    wconv_k<<<dim3(12, 48, 12), 256, 0, stream>>>(W2, W2T,  3072, 768, (size_t)768 * 3072);
    wconv_k<<<dim3(12, 12, 1),  256, 0, stream>>>(W_patch, WpT, 768, 768, 0);
    whT_k  <<<dim3(16, 12),     256, 0, stream>>>(W_head, WhT);

    // patch embed pipeline
    patch_ln_k<<<12544, 256, 0, stream>>>(x, XA, ln_p_g, ln_p_b);
    mgemm_k<1, float><<<dim3(6, 98), 256, 0, stream>>>(XA, WpT, b_patch, nullptr, PE, 12544, 768, 768);
    ln_k<float><<<12544, 256, 0, stream>>>(PE, E2, ln_e_g, ln_e_b);
    build_z_k<<<37824, 256, 0, stream>>>(E2, cls_tok, pos_emb, Z);

    for (int i = 0; i < 12; ++i) {
        bf* WQKVT_i = WQKVT + (size_t)i * QKVS;
        bf* WoT_i   = WoT + (size_t)i * 768 * 768;
        bf* W1T_i   = W1T + (size_t)i * 3072 * 768;
        bf* W2T_i   = W2T + (size_t)i * 768 * 3072;

        ln_k<bf><<<M, 256, 0, stream>>>(Z, XA, ln_a_g + (size_t)i * 768, ln_a_b + (size_t)i * 768);
        mgemm_k<0, bf><<<dim3(18, 99), 256, 0, stream>>>(XA, WQKVT_i, nullptr, nullptr, QKV, M, 2304, 768);
        attn_k<<<dim3(12, 64), 256, 0, stream>>>(QKV, OB);
        mgemm_k<3, float><<<dim3(6, 99), 256, 0, stream>>>(OB, WoT_i, bo + (size_t)i * 768, Z, Z, M, 768, 768);
        ln_k<bf><<<M, 256, 0, stream>>>(Z, XA, ln_f_g + (size_t)i * 768, ln_f_b + (size_t)i * 768);
        mgemm_k<2, bf><<<dim3(24, 99), 256, 0, stream>>>(XA, W1T_i, b1 + (size_t)i * 3072, nullptr, FFH, M, 3072, 768);
        mgemm_k<3, float><<<dim3(6, 99), 256, 0, stream>>>(FFH, W2T_i, b2 + (size_t)i * 768, Z, Z, M, 768, 3072);
    }

    // head: LN(CLS rows) -> logits GEMM -> softmax
    ln_cls_k<<<128, 256, 0, stream>>>(Z, CLS, ln_out_g, ln_out_b);
    mgemm_k<0, float><<<dim3(8, 1), 256, 0, stream>>>(CLS, WhT, nullptr, nullptr, LOG, 64, 1024, 768);
    shead_k<<<64, 256, 0, stream>>>(LOG, b_head, (float*)d_out);
}